// Round 13
// baseline (525.557 us; speedup 1.0000x reference)
//
#include <hip/hip_runtime.h>
#include <hip/hip_cooperative_groups.h>
#include <math.h>

namespace cg = cooperative_groups;

#define NPn 30000
#define EPn 480000
#define NLl 48
#define ELl 144
#define Tn 96
#define NAn 11
#define Dn 256
#define N1 49
#define NEGf (-1000000000.0f)
#define NSTATES 97
#define CHN 125
#define PC 13
#define YN (N1*PC)       // 637
#define SMEM_SZ 27648

struct KParams {
  const int *src_p, *dst_p; const float* x_p;
  const int* lab_in; const int *bfs_i, *bfs_b;
  const float* xg; const int *srcl, *dstl;
  const float *Wp1,*bp1,*Wp2,*bp2,*Wl1,*bl1,*Wl2,*bl2,*Wd1,*bd1,*Wd2,*bd2,*Wg,*Wh,*bh;
  int* deg; float* odegw; float* xagg; float* zr;
  float* rs_g; float* Pm; float* Qp; float* Ql;
  float* m_arr; float* e_arr; int* rec; int* dirs; int* dird;
  int* lab_idx; float* lab_means; int* Sval; float* spart;
  float* out;
  int zwords;
};

__global__ __launch_bounds__(256) void k_all(KParams p){
  __shared__ __align__(16) char smem[SMEM_SZ];
  cg::grid_group grid = cg::this_grid();
  const int bid = blockIdx.x;
  const int tid = threadIdx.x;
  const int nb  = gridDim.x;

  // ================= P0a: zero-init workspace =================
  {
    int* base = (int*)p.deg;   // deg is the start of the zero region
    for (int i = bid*256 + tid; i < p.zwords; i += nb*256) base[i] = 0;
  }
  grid.sync();

  // ================= P0b: sim | lig | pre | deg =================
  if (bid == 0){
    // ---------- control sim ----------
    int*   sv    = (int*)(smem+0);
    int*   sb    = (int*)(smem+384);
    int*   qarr  = (int*)(smem+768);
    int2*  ctrl  = (int2*)(smem+1168);
    float* valuA = (float*)(smem+1936);
    float* valvA = (float*)(smem+2320);
    float* baseB = (float*)(smem+2704);          // [Tn][N1]
    int*   slab  = (int*)(smem+21520);
    int*   cntL  = (int*)(smem+21728);
    if (tid < Tn){ sv[tid]=p.bfs_i[2*tid+1]; sb[tid]=p.bfs_b[tid]; }
    if (tid <= Tn) qarr[tid]=0;
    if (tid < NAn) cntL[tid]=0;
    if (tid < N1){ int l=(tid<NLl)? p.lab_in[tid] : (NAn-1); slab[tid]=l; p.lab_idx[tid]=l; }
    __syncthreads();
    if (tid < NLl) atomicAdd(&cntL[slab[tid]],1);
    if (tid == 0) qarr[0]=p.bfs_i[0];
    __syncthreads();
    if (tid < NAn){
      int c=cntL[tid];
      p.lab_means[tid]     = ((float)c + ((tid==NAn-1)?1.f:0.f))*(1.0f/49.0f);
      p.lab_means[NAn+tid] = (float)c*(1.0f/48.0f);
    }
    if (tid == 0){
      p.dirs[192]=qarr[0]; p.dird[192]=p.bfs_i[1];
      int head=0, tail=1, ec=0, timec=0;
      for (int t=0;t<Tn;t++){
        int v = sv[t], bix = sb[t];
        int active = (tail>head)?1:0;
        int h = (head<=Tn)? head : Tn;
        int u = qarr[h];
        int is_stop = (v==NLl)?1:0;
        int pop = active & is_stop;
        int doe = active & (is_stop^1);
        ctrl[t] = make_int2(u | (doe<<8) | (pop<<9) | (active<<10) | (timec<<16), v | (bix<<8));
        if (doe){
          if (tail<=Tn) qarr[tail]=v;
          if (ec<192){ p.dirs[ec]=u; p.dird[ec]=v; p.dirs[ec+1]=v; p.dird[ec+1]=u; }
        }
        head+=pop; tail+=doe; ec+=2*doe; timec+=doe;
      }
      p.Sval[0]=ec/2;
    }
    __syncthreads();
    if (tid < Tn){
      int2 c=ctrl[tid];
      p.rec[tid]=c.x&255; p.rec[Tn+tid]=c.y&255; p.rec[2*Tn+tid]=(c.y>>8)&3;
      p.rec[3*Tn+tid]=(c.x>>10)&1; p.rec[4*Tn+tid]=(c.x>>8)&1; p.rec[5*Tn+tid]=(c.x>>16)&255;
    }
    __syncthreads();
    if (tid < 64){
      const int l = tid;
      int labv = (l<N1)? slab[l] : (NAn-1);
      float val;
      switch(labv){
        case 0: val=4.f; break; case 1: val=1.f; break; case 2: val=3.f; break;
        case 3: val=1.f; break; case 4: val=2.f; break; case 5: val=1.f; break;
        case 6: val=5.f; break; case 7: val=1.f; break; case 8: val=6.f; break;
        case 9: val=1.f; break; default: val=1000.f; break;
      }
      if (l>=N1) val=0.f;
      int closed=0;
      unsigned long long adjm=0ull;
      #pragma unroll 4
      for (int t=0;t<Tn;t++){
        int2 c=ctrl[t];
        int u=c.x&255, doe=(c.x>>8)&1, pop=(c.x>>9)&1;
        int v=c.y&255, bix=(c.y>>8)&3;
        float base = (val<1.f || closed || ((adjm>>u)&1ull)) ? NEGf : 0.f;
        if (l==u) base=NEGf;
        if (l<N1) baseB[t*N1+l]=base;
        if (l==u) valuA[t]=val;
        if (l==v) valvA[t]=val;
        if (doe){
          float dec = (bix==0)?1.f:(bix==1)?2.f:(bix==2)?3.f:1.5f;
          if (l==u){ val-=dec; adjm |= (1ull<<v); }
          if (l==v){ val-=dec; adjm |= (1ull<<u); }
        }
        if (pop && l==u) closed=1;
      }
    }
    __syncthreads();
    {
      const int lane=tid&63, wv=tid>>6;
      for (int t=wv; t<Tn; t+=4){
        float valu=valuA[t], valv=valvA[t];
        int v=sv[t], bix=sb[t];
        if (lane<N1){
          float mnou = (valu<1.f)? NEGf : baseB[t*N1+lane];
          float m = mnou;
          if (lane==v) m=0.f;
          if (lane==NLl) m=0.f;
          p.m_arr[t*N1+lane]=m;
        }
        if (lane<4){
          float mnv = (valu<1.f)? NEGf : baseB[t*N1+v];
          float mv = fminf(valu,valv);
          float e;
          if (mv<=0.f) e=NEGf;
          else if (mv<=1.f) e=((lane==1)||(lane==2))?NEGf:0.f;
          else if (mv<=2.f) e=(lane==2)?NEGf:0.f;
          else e=0.f;
          if (mnv <= NEGf*0.5f) e=NEGf;
          if (lane==bix) e=0.f;
          p.e_arr[t*4+lane]=e;
        }
      }
    }
  } else if (bid == 1){
    // ---------- ligand GCN: rs only ----------
    float* sW    = (float*)(smem+0);
    float* sagg  = (float*)(smem+15360);   // [NLl][16], 16-aligned
    float* ow    = (float*)(smem+18432);
    float* sdinv = (float*)(smem+18624);
    int*   sdeg  = (int*)(smem+18816);
    int*   ses   = (int*)(smem+19008);
    int*   sed   = (int*)(smem+19584);
    int*   slab2 = (int*)(smem+20160);
    if (tid<NLl){ sdeg[tid]=1; slab2[tid]=p.lab_in[tid]; }
    for (int i=tid;i<NLl*16;i+=256) sagg[i]=0.f;
    for (int i=tid;i<15*Dn;i+=256) sW[i]=p.Wl1[i];
    __syncthreads();
    if (tid<ELl){ ses[tid]=p.srcl[tid]; sed[tid]=p.dstl[tid]; atomicAdd(&sdeg[p.dstl[tid]],1); }
    __syncthreads();
    if (tid<NLl) sdinv[tid]=rsqrtf((float)sdeg[tid]);
    __syncthreads();
    if (tid<NLl){
      float dv=sdinv[tid];
      ow[tid]=dv;
      for (int q=0;q<4;q++) sagg[tid*16+q]=p.xg[tid*4+q]*dv;
      sagg[tid*16+4+slab2[tid]]=dv;
    }
    __syncthreads();
    if (tid<ELl){
      int s=ses[tid], d=sed[tid];
      float dvs=sdinv[s];
      for (int q=0;q<4;q++) atomicAdd(&sagg[d*16+q], p.xg[s*4+q]*dvs);
      atomicAdd(&sagg[d*16+4+slab2[s]], dvs);
      atomicAdd(&ow[s], sdinv[d]);
    }
    __syncthreads();
    {
      int c=tid;
      float wcol[16];
      #pragma unroll
      for (int q=0;q<15;q++) wcol[q]=sW[q*Dn+c];
      wcol[15]=0.f;
      float b=p.bl1[c];
      float rsum=0.f;
      for (int d=0;d<NLl;d++){
        const float4* ar=(const float4*)&sagg[d*16];
        float4 x0=ar[0],x1=ar[1],x2=ar[2],x3=ar[3];
        float a=0.f;
        a=fmaf(x0.x,wcol[0],a); a=fmaf(x0.y,wcol[1],a); a=fmaf(x0.z,wcol[2],a); a=fmaf(x0.w,wcol[3],a);
        a=fmaf(x1.x,wcol[4],a); a=fmaf(x1.y,wcol[5],a); a=fmaf(x1.z,wcol[6],a); a=fmaf(x1.w,wcol[7],a);
        a=fmaf(x2.x,wcol[8],a); a=fmaf(x2.y,wcol[9],a); a=fmaf(x2.z,wcol[10],a); a=fmaf(x2.w,wcol[11],a);
        a=fmaf(x3.x,wcol[12],a); a=fmaf(x3.y,wcol[13],a); a=fmaf(x3.z,wcol[14],a);
        float h=fmaxf(sdinv[d]*a + b, 0.f);
        rsum = fmaf(sdinv[d]*ow[d], h, rsum);
      }
      p.rs_g[c]=rsum*(1.0f/48.0f);
    }
  } else if (bid < 66){
    // ---------- pre: Pm/Qp/Ql rows, one k per wave ----------
    const int lane = tid&63, wv = tid>>6;
    const int k = (bid-2)*4 + wv;
    float pg=0.f;
    float4 pu=make_float4(0,0,0,0), pv=make_float4(0,0,0,0), ph=make_float4(0,0,0,0);
    float4 qp=make_float4(0,0,0,0), ql=make_float4(0,0,0,0);
    for (int q=0;q<4;q++){
      int n = lane + 64*q;
      float w = p.Wd2[(size_t)k*Dn+n];
      pg = fmaf(w, p.Wg[524+n], pg);
      float4 a=*(const float4*)&p.Wh[(size_t)(257+n)*4];
      float4 b=*(const float4*)&p.Wh[(size_t)(524+n)*4];
      float4 c=*(const float4*)&p.Wh[(size_t)(791+n)*4];
      pu.x=fmaf(w,a.x,pu.x); pu.y=fmaf(w,a.y,pu.y); pu.z=fmaf(w,a.z,pu.z); pu.w=fmaf(w,a.w,pu.w);
      pv.x=fmaf(w,b.x,pv.x); pv.y=fmaf(w,b.y,pv.y); pv.z=fmaf(w,b.z,pv.z); pv.w=fmaf(w,b.w,pv.w);
      ph.x=fmaf(w,c.x,ph.x); ph.y=fmaf(w,c.y,ph.y); ph.z=fmaf(w,c.z,ph.z); ph.w=fmaf(w,c.w,ph.w);
      float wp = p.Wp2[(size_t)k*Dn+n];
      float wl = p.Wl2[(size_t)k*Dn+n];
      float4 w1=*(const float4*)&p.Wh[(size_t)(1+n)*4];
      float4 w2=*(const float4*)&p.Wh[(size_t)(1058+n)*4];
      qp.x=fmaf(wp,w1.x,qp.x); qp.y=fmaf(wp,w1.y,qp.y); qp.z=fmaf(wp,w1.z,qp.z); qp.w=fmaf(wp,w1.w,qp.w);
      ql.x=fmaf(wl,w2.x,ql.x); ql.y=fmaf(wl,w2.y,ql.y); ql.z=fmaf(wl,w2.z,ql.z); ql.w=fmaf(wl,w2.w,ql.w);
    }
    for (int off=32; off>0; off>>=1){
      pg += __shfl_xor(pg,off);
      pu.x+=__shfl_xor(pu.x,off); pu.y+=__shfl_xor(pu.y,off); pu.z+=__shfl_xor(pu.z,off); pu.w+=__shfl_xor(pu.w,off);
      pv.x+=__shfl_xor(pv.x,off); pv.y+=__shfl_xor(pv.y,off); pv.z+=__shfl_xor(pv.z,off); pv.w+=__shfl_xor(pv.w,off);
      ph.x+=__shfl_xor(ph.x,off); ph.y+=__shfl_xor(ph.y,off); ph.z+=__shfl_xor(ph.z,off); ph.w+=__shfl_xor(ph.w,off);
      qp.x+=__shfl_xor(qp.x,off); qp.y+=__shfl_xor(qp.y,off); qp.z+=__shfl_xor(qp.z,off); qp.w+=__shfl_xor(qp.w,off);
      ql.x+=__shfl_xor(ql.x,off); ql.y+=__shfl_xor(ql.y,off); ql.z+=__shfl_xor(ql.z,off); ql.w+=__shfl_xor(ql.w,off);
    }
    if (lane==0){
      float* o = p.Pm + k*PC;
      o[0]=pg; o[1]=pu.x; o[2]=pu.y; o[3]=pu.z; o[4]=pu.w;
      o[5]=pv.x; o[6]=pv.y; o[7]=pv.z; o[8]=pv.w;
      o[9]=ph.x; o[10]=ph.y; o[11]=ph.z; o[12]=ph.w;
      *(float4*)&p.Qp[k*4] = qp;
      *(float4*)&p.Ql[k*4] = ql;
    }
  } else {
    // ---------- deg atomics (grid-stride) ----------
    for (int e=(bid-66)*256+tid; e<EPn; e += (nb-66)*256)
      atomicAdd(&p.deg[p.dst_p[e]], 1);
  }
  grid.sync();

  // ================= P1: dcp (b0..96) | xagg (b97..) =================
  if (bid < NSTATES){
    int k = bid;
    if (k <= p.Sval[0]){
      float* cnt   = (float*)(smem+0);
      float* y1    = (float*)(smem+2176);
      float* za    = (float*)(smem+4736);
      float* sdinv = (float*)(smem+7296);
      int*   sdeg  = (int*)(smem+7504);
      int*   se    = (int*)(smem+7712);
      int*   sd    = (int*)(smem+8480);
      int*   slab  = (int*)(smem+9248);
      int*   srec  = (int*)(smem+9456);
      float* hTc   = (float*)(smem+11760);   // [64][N1]
      float* sPc   = (float*)(smem+24304);   // [64][PC]
      int ecnt = (k==0)?1:(2*k);
      int base = (k==0)?192:0;
      if (tid<N1){ sdeg[tid]=1; slab[tid]=p.lab_idx[tid]; }
      for (int i=tid;i<N1*11;i+=256) cnt[i]=0.f;
      for (int i=tid;i<YN;i+=256) y1[i]=0.f;
      for (int i=tid;i<6*Tn;i+=256) srec[i]=p.rec[i];
      __syncthreads();
      if (tid<ecnt){ se[tid]=p.dirs[base+tid]; sd[tid]=p.dird[base+tid]; atomicAdd(&sdeg[sd[tid]],1); }
      __syncthreads();
      if (tid<N1) sdinv[tid]=rsqrtf((float)sdeg[tid]);
      __syncthreads();
      if (tid<N1) cnt[tid*11+slab[tid]] = sdinv[tid];
      __syncthreads();
      if (tid<ecnt) atomicAdd(&cnt[sd[tid]*11+slab[se[tid]]], sdinv[se[tid]]);
      __syncthreads();
      // chunked hT: 4 chunks of 64 columns
      for (int ch=0; ch<4; ch++){
        if (tid<64){
          int c = ch*64 + tid;
          float wreg[11];
          #pragma unroll
          for (int a=0;a<11;a++) wreg[a]=p.Wd1[a*Dn+c];
          float bb=p.bd1[c];
          for (int r=0;r<N1;r++){
            float s=0.f;
            #pragma unroll
            for (int a=0;a<11;a++) s=fmaf(cnt[r*11+a], wreg[a], s);
            hTc[tid*N1+r]=fmaxf(sdinv[r]*s + bb, 0.f);
          }
        }
        for (int i=tid;i<64*PC;i+=256) sPc[i]=p.Pm[ch*64*PC + i];
        __syncthreads();
        for (int idx=tid; idx<YN; idx+=256){
          int r=idx/PC, j=idx-r*PC;
          float acc=0.f;
          for (int cp=0;cp<64;cp++) acc=fmaf(hTc[cp*N1+r], sPc[cp*PC+j], acc);
          y1[idx]+=acc;
        }
        __syncthreads();
      }
      for (int idx=tid; idx<YN; idx+=256){
        int r=idx/PC;
        za[idx]=sdinv[r]*y1[idx];
      }
      __syncthreads();
      for (int i=tid; i<ecnt*PC; i+=256){
        int e=i/PC, j=i-e*PC;
        atomicAdd(&za[sd[e]*PC+j], sdinv[se[e]]*y1[se[e]*PC+j]);
      }
      __syncthreads();
      for (int idx=tid; idx<YN; idx+=256){
        int r=idx/PC;
        za[idx]=sdinv[r]*za[idx];
      }
      __syncthreads();
      if (tid<64){
        const int lane=tid;
        for (int t=0;t<Tn;t++){
          if (!srec[3*Tn+t] || srec[5*Tn+t]!=k) continue;
          const int u=srec[t], v=srec[Tn+t], doe=srec[4*Tn+t];
          float g = -INFINITY;
          float4 hm = make_float4(0,0,0,0);
          if (lane<N1){
            const float* zrow = za + lane*PC;
            g = zrow[0] + p.Wg[780+slab[lane]] + p.m_arr[t*N1+lane];
            hm.x=zrow[9]; hm.y=zrow[10]; hm.z=zrow[11]; hm.w=zrow[12];
          }
          float gv = __shfl(g, v);
          float gM = g;
          for (int off=32; off>0; off>>=1) gM = fmaxf(gM, __shfl_xor(gM, off));
          float ex = (lane<N1)? expf(g-gM) : 0.f;
          float gS = ex;
          for (int off=32; off>0; off>>=1){
            gS += __shfl_xor(gS, off);
            hm.x+=__shfl_xor(hm.x,off); hm.y+=__shfl_xor(hm.y,off);
            hm.z+=__shfl_xor(hm.z,off); hm.w+=__shfl_xor(hm.w,off);
          }
          if (lane==0){
            p.spart[t*5] = gv - gM - logf(gS);
            if (doe){
              const int lu=slab[u], lv=slab[v];
              const float tf=(float)k;
              for (int j=0;j<4;j++){
                float hmj = (j==0)?hm.x:(j==1)?hm.y:(j==2)?hm.z:hm.w;
                p.spart[t*5+1+j] = tf*p.Wh[j] + p.Wh[(513+lu)*4+j] + p.Wh[(780+lv)*4+j]
                     + za[u*PC+1+j] + za[v*PC+5+j] + hmj*(1.0f/49.0f) + p.e_arr[4*t+j];
              }
            }
          }
        }
      }
    }
  } else {
    // ---------- xagg scatter (grid-stride, 16 lanes/edge) ----------
    const long tot = (long)EPn*16;
    const long stride = (long)(nb-NSTATES)*256;
    for (long g=(long)(bid-NSTATES)*256+tid; g<tot; g+=stride){
      int e = (int)(g>>4), c = (int)(g&15);
      int s = p.src_p[e], d = p.dst_p[e];
      if (c < 15){
        float dvs = rsqrtf((float)(p.deg[s]+1));
        atomicAdd(&p.xagg[d*16+c], p.x_p[s*15+c]*dvs);
      } else {
        float dvd = rsqrtf((float)(p.deg[d]+1));
        atomicAdd(&p.odegw[s], dvd);
      }
    }
  }
  grid.sync();

  // ================= P2: fuse (240 chunks, grid-stride) =================
  for (int chk=bid; chk<NPn/CHN; chk+=nb){
    float* sx = (float*)(smem+0);        // [CHN][16]
    float* sc = (float*)(smem+CHN*16*4);
    int base = chk*CHN;
    float wcol[15];
    for (int kk=0;kk<15;kk++) wcol[kk]=p.Wp1[kk*Dn+tid];
    float b = p.bp1[tid];
    for (int i=tid;i<CHN*16;i+=256){
      int n = base+(i>>4), c = i&15;
      float v = 0.f;
      if (c<15){
        float dv = rsqrtf((float)(p.deg[n]+1));
        v = (p.xagg[n*16+c] + p.x_p[n*15+c]*dv)*dv;
      }
      sx[i]=v;
    }
    for (int i=tid;i<CHN;i+=256){
      int n = base+i;
      float dv = rsqrtf((float)(p.deg[n]+1));
      sc[i] = dv*(p.odegw[n]+dv);
    }
    __syncthreads();
    float acc = 0.f;
    for (int i=0;i<CHN;i++){
      float d0 = b;
      for (int kk=0;kk<15;kk++) d0 = fmaf(sx[i*16+kk], wcol[kk], d0);
      acc = fmaf(sc[i], fmaxf(d0,0.f), acc);
    }
    atomicAdd(&p.zr[tid], acc);
    __syncthreads();
  }
  grid.sync();

  // ================= P3: final (block 0) =================
  if (bid == 0){
    float* sr   = (float*)(smem+0);
    float* rsg  = (float*)(smem+1024);
    float* hc4s = (float*)(smem+2048);
    float* red  = (float*)(smem+2064);
    sr[tid]=p.zr[tid]*(1.0f/30000.0f);
    rsg[tid]=p.rs_g[tid];
    __syncthreads();
    if (tid<64){
      int lane=tid;
      float4 h=make_float4(0,0,0,0);
      for (int q=0;q<4;q++){
        int n=lane+64*q;
        float srn=sr[n], rsn=rsg[n], bpn=p.bp2[n], bln=p.bl2[n], bdn=p.bd2[n];
        float4 qp=*(const float4*)&p.Qp[n*4];
        float4 ql=*(const float4*)&p.Ql[n*4];
        float4 w1=*(const float4*)&p.Wh[(size_t)(1+n)*4];
        float4 w2=*(const float4*)&p.Wh[(size_t)(1058+n)*4];
        float4 wu=*(const float4*)&p.Wh[(size_t)(257+n)*4];
        float4 wv=*(const float4*)&p.Wh[(size_t)(524+n)*4];
        float4 wh=*(const float4*)&p.Wh[(size_t)(791+n)*4];
        h.x += srn*qp.x + rsn*ql.x + bpn*w1.x + bln*w2.x + bdn*(wu.x+wv.x+wh.x);
        h.y += srn*qp.y + rsn*ql.y + bpn*w1.y + bln*w2.y + bdn*(wu.y+wv.y+wh.y);
        h.z += srn*qp.z + rsn*ql.z + bpn*w1.z + bln*w2.z + bdn*(wu.z+wv.z+wh.z);
        h.w += srn*qp.w + rsn*ql.w + bpn*w1.w + bln*w2.w + bdn*(wu.w+wv.w+wh.w);
      }
      if (lane<NAn){
        float4 wa=*(const float4*)&p.Wh[(size_t)(1047+lane)*4];
        float4 wb=*(const float4*)&p.Wh[(size_t)(1314+lane)*4];
        float aa=p.lab_means[lane], bb=p.lab_means[NAn+lane];
        h.x += aa*wa.x + bb*wb.x; h.y += aa*wa.y + bb*wb.y;
        h.z += aa*wa.z + bb*wb.z; h.w += aa*wa.w + bb*wb.w;
      }
      for (int off=32; off>0; off>>=1){
        h.x+=__shfl_xor(h.x,off); h.y+=__shfl_xor(h.y,off);
        h.z+=__shfl_xor(h.z,off); h.w+=__shfl_xor(h.w,off);
      }
      if (lane==0){
        hc4s[0]=h.x+p.bh[0]; hc4s[1]=h.y+p.bh[1]; hc4s[2]=h.z+p.bh[2]; hc4s[3]=h.w+p.bh[3];
      }
    }
    __syncthreads();
    if (tid<Tn){
      int t=tid;
      float res=0.f;
      if (p.rec[3*Tn+t]){
        res = p.spart[t*5];
        if (p.rec[4*Tn+t]){
          int bidx = p.rec[2*Tn+t];
          float h0=p.spart[t*5+1]+hc4s[0];
          float h1=p.spart[t*5+2]+hc4s[1];
          float h2=p.spart[t*5+3]+hc4s[2];
          float h3=p.spart[t*5+4]+hc4s[3];
          float M=fmaxf(fmaxf(h0,h1),fmaxf(h2,h3));
          float se2=expf(h0-M)+expf(h1-M)+expf(h2-M)+expf(h3-M);
          float hb=(bidx==0)?h0:(bidx==1)?h1:(bidx==2)?h2:h3;
          res += hb - M - logf(se2);
        }
      }
      red[t]=res;
    }
    __syncthreads();
    if (tid==0){
      float s=0.f;
      for (int t=0;t<Tn;t++) s+=red[t];
      p.out[0]=s;
    }
  }
}

// ================= launch =================

extern "C" void kernel_launch(void* const* d_in, const int* in_sizes, int n_in,
                              void* d_out, int out_size, void* d_ws, size_t ws_size,
                              hipStream_t stream){
  KParams p;
  p.src_p    =(const int*)d_in[1];
  p.dst_p    =(const int*)d_in[2];
  p.x_p      =(const float*)d_in[0];
  p.lab_in   =(const int*)d_in[4];
  p.bfs_i    =(const int*)d_in[7];
  p.bfs_b    =(const int*)d_in[8];
  p.xg       =(const float*)d_in[3];
  p.srcl     =(const int*)d_in[5];
  p.dstl     =(const int*)d_in[6];
  p.Wp1=(const float*)d_in[9];  p.bp1=(const float*)d_in[10];
  p.Wp2=(const float*)d_in[11]; p.bp2=(const float*)d_in[12];
  p.Wl1=(const float*)d_in[13]; p.bl1=(const float*)d_in[14];
  p.Wl2=(const float*)d_in[15]; p.bl2=(const float*)d_in[16];
  p.Wd1=(const float*)d_in[17]; p.bd1=(const float*)d_in[18];
  p.Wd2=(const float*)d_in[19]; p.bd2=(const float*)d_in[20];
  p.Wg =(const float*)d_in[23];
  p.Wh =(const float*)d_in[25];
  p.bh =(const float*)d_in[26];

  char* w=(char*)d_ws;
  size_t off=0;
  auto alloc=[&](size_t bytes)->char*{ char* pb=w+off; off=(off+bytes+255)&~((size_t)255); return pb; };
  // ---- contiguous zero-init region (deg first; zwords spans through zr) ----
  p.deg   =(int*)alloc((size_t)NPn*4);
  p.odegw =(float*)alloc((size_t)NPn*4);
  p.xagg  =(float*)alloc((size_t)NPn*16*4);
  p.zr    =(float*)alloc(Dn*4);
  p.zwords = (int)(off/4);          // zero everything from deg through zr (incl. padding)
  // ---- rest (fully written before read) ----
  p.rs_g  =(float*)alloc(Dn*4);
  p.Pm    =(float*)alloc(Dn*PC*4);
  p.Qp    =(float*)alloc(Dn*4*4);
  p.Ql    =(float*)alloc(Dn*4*4);
  p.m_arr =(float*)alloc((size_t)Tn*N1*4);
  p.e_arr =(float*)alloc((size_t)Tn*4*4);
  p.rec   =(int*)alloc((size_t)6*Tn*4);
  p.dirs  =(int*)alloc(194*4);
  p.dird  =(int*)alloc(194*4);
  p.lab_idx=(int*)alloc(N1*4);
  p.lab_means=(float*)alloc(2*NAn*4);
  p.Sval  =(int*)alloc(4);
  p.spart =(float*)alloc((size_t)Tn*5*4);
  p.out   =(float*)d_out;
  (void)in_sizes;(void)n_in;(void)ws_size;(void)out_size;

  int maxB = 0;
  if (hipOccupancyMaxActiveBlocksPerMultiprocessor(&maxB, (const void*)k_all, 256, 0) != hipSuccess || maxB < 1)
    maxB = 2;
  int grid = maxB * 256;            // 256 CUs on MI355X
  if (grid > 1024) grid = 1024;
  if (grid < 256)  grid = 256;

  void* args[] = { (void*)&p };
  hipLaunchCooperativeKernel((const void*)k_all, dim3(grid), dim3(256), args, 0, stream);
}